// Round 1
// baseline (1488.800 us; speedup 1.0000x reference)
//
#include <hip/hip_runtime.h>
#include <hip/hip_bf16.h>
#include <cstdint>
#include <cstddef>

// Shapes: B=16, C=1024, H=W=32 -> N=1024, T=77, NH=8, HD=128
// q[b,c,n] = sum Wq[c,k]Vx[b,k,n] + bq      (c,k in 0..1023)
// kv[b,e,t] = sum Wkv[e,k]Tx[b,k,t] + bkv   (e in 0..2047)
//   k[b,h,d,t] = kv[b, h*256 + d, t];  v[b,h,d,t] = kv[b, h*256 + 128 + d, t]
// attn per (b,h): S[n,t] = sum_d q[b,h*128+d,n] k[.,t];  P = softmax(S*scale)
// o[b, h*128+d, n] = sum_t v[d,t] P[n,t]
// out[b,c,n] = sum Wp[c,k] o[b,k,n] + bp

// ---------------------------------------------------------------------------
// Big projection GEMM: Y[b][d][n] = sum_c W[d][c] * X[b][c][n] + bias[d]
// K = 1024, 64x64 tile, BK=16, 4x4 micro-tile, 256 threads.
// ---------------------------------------------------------------------------
__global__ __launch_bounds__(256) void gemm_proj(
    const float* __restrict__ W, const float* __restrict__ X,
    const float* __restrict__ bias, float* __restrict__ Y)
{
  const int b   = blockIdx.z;
  const int d0  = blockIdx.y * 64;
  const int n0  = blockIdx.x * 64;
  const int tid = threadIdx.x;
  const int tx  = tid & 15;   // n sub-tile
  const int ty  = tid >> 4;   // d sub-tile

  __shared__ float As[16][68];  // [kk][d_local], transposed, padded (16B-aligned rows)
  __shared__ float Bs[16][68];  // [kk][n_local]

  const float* Xb = X + (size_t)b * (1024u * 1024u);
  float acc[4][4] = {{0.f, 0.f, 0.f, 0.f}};

  const int ar = tid >> 2;        // 0..63  (d row of A tile)
  const int ac = (tid & 3) * 4;   // 0,4,8,12 (k col group)
  const int br = tid >> 4;        // 0..15  (k row of B tile)
  const int bc = (tid & 15) * 4;  // n col group

  for (int k0 = 0; k0 < 1024; k0 += 16) {
    float4 av = *(const float4*)(W  + (size_t)(d0 + ar) * 1024 + (k0 + ac));
    float4 bv = *(const float4*)(Xb + (size_t)(k0 + br) * 1024 + (n0 + bc));
    As[ac + 0][ar] = av.x;
    As[ac + 1][ar] = av.y;
    As[ac + 2][ar] = av.z;
    As[ac + 3][ar] = av.w;
    *(float4*)&Bs[br][bc] = bv;
    __syncthreads();
#pragma unroll
    for (int kk = 0; kk < 16; ++kk) {
      float4 a  = *(const float4*)&As[kk][ty * 4];
      float4 bb = *(const float4*)&Bs[kk][tx * 4];
      const float* af = (const float*)&a;
      const float* bf = (const float*)&bb;
#pragma unroll
      for (int i = 0; i < 4; ++i)
#pragma unroll
        for (int j = 0; j < 4; ++j)
          acc[i][j] += af[i] * bf[j];
    }
    __syncthreads();
  }

#pragma unroll
  for (int i = 0; i < 4; ++i) {
    const int d = d0 + ty * 4 + i;
    const float bv = bias[d];
    float4 o;
    o.x = acc[i][0] + bv;
    o.y = acc[i][1] + bv;
    o.z = acc[i][2] + bv;
    o.w = acc[i][3] + bv;
    *(float4*)(Y + ((size_t)b * 1024 + d) * 1024 + n0 + tx * 4) = o;
  }
}

// ---------------------------------------------------------------------------
// KV projection: kvout[b][e][t] = sum_c Wkv[e][c] * Tx[b][c][t] + bkv[e]
// e-tile = 128 rows/block, each thread: 2 rows x 20 t-slots (t padded to 80).
// ---------------------------------------------------------------------------
__global__ __launch_bounds__(256) void gemm_kv(
    const float* __restrict__ Wkv, const float* __restrict__ Tx,
    const float* __restrict__ bkv, float* __restrict__ kvout)
{
  const int b   = blockIdx.y;
  const int e0  = blockIdx.x * 128;
  const int tid = threadIdx.x;

  __shared__ float Wts[32][132];  // [kk][row] transposed; 132 -> 16B-aligned rows
  __shared__ float Txs[32][80];   // [kk][t], t padded to 80 (pad zeroed)

  const int row0 = (tid >> 2) * 2;   // 0..126
  const int tb   = (tid & 3) * 20;   // 0,20,40,60

  float acc[2][20];
#pragma unroll
  for (int r = 0; r < 2; ++r)
#pragma unroll
    for (int j = 0; j < 20; ++j) acc[r][j] = 0.f;

  // zero the t-pad once (stays zero; W/Tx loads never touch cols 77..79)
  for (int idx = tid; idx < 32 * 3; idx += 256) {
    int r = idx / 3, c = 77 + (idx - r * 3);
    Txs[r][c] = 0.f;
  }

  const int wrow = tid >> 1;        // 0..127
  const int wkg  = (tid & 1) * 16;  // 0 or 16

  for (int k0 = 0; k0 < 1024; k0 += 32) {
    __syncthreads();
    // W tile: rows e0..e0+127, cols k0..k0+31 (transposed into LDS)
#pragma unroll
    for (int i = 0; i < 4; ++i) {
      float4 w = *(const float4*)(Wkv + (size_t)(e0 + wrow) * 1024 + k0 + wkg + i * 4);
      Wts[wkg + i * 4 + 0][wrow] = w.x;
      Wts[wkg + i * 4 + 1][wrow] = w.y;
      Wts[wkg + i * 4 + 2][wrow] = w.z;
      Wts[wkg + i * 4 + 3][wrow] = w.w;
    }
    // Tx tile: rows k0..k0+31 are contiguous 32*77 floats
    const float* src = Tx + ((size_t)b * 1024 + k0) * 77;
    for (int idx = tid; idx < 32 * 77; idx += 256) {
      int r = idx / 77, c = idx - r * 77;
      Txs[r][c] = src[idx];
    }
    __syncthreads();
#pragma unroll
    for (int kk = 0; kk < 32; ++kk) {
      float2 w = *(const float2*)&Wts[kk][row0];
#pragma unroll
      for (int tc = 0; tc < 5; ++tc) {
        float4 x4 = *(const float4*)&Txs[kk][tb + tc * 4];
        const float* xf = (const float*)&x4;
#pragma unroll
        for (int j = 0; j < 4; ++j) {
          acc[0][tc * 4 + j] += w.x * xf[j];
          acc[1][tc * 4 + j] += w.y * xf[j];
        }
      }
    }
  }

#pragma unroll
  for (int r = 0; r < 2; ++r) {
    const int e = e0 + row0 + r;
    const float bv = bkv[e];
    float* dst = kvout + ((size_t)b * 2048 + e) * 77;
#pragma unroll
    for (int j = 0; j < 20; ++j) {
      int t = tb + j;
      if (t < 77) dst[t] = acc[r][j] + bv;
    }
  }
}

// ---------------------------------------------------------------------------
// Fused attention per (b, h, 256-n chunk). K then V staged in LDS (77->80 pad,
// pad zeroed). 77 scores live in registers; softmax in-thread.
// ---------------------------------------------------------------------------
__global__ __launch_bounds__(256) void attn_kernel(
    const float* __restrict__ q,   // [B][1024][1024]
    const float* __restrict__ kv,  // [B][2048][77]
    float* __restrict__ o)         // [B][1024][1024]
{
  const int b   = blockIdx.z;
  const int h   = blockIdx.y;
  const int n0  = blockIdx.x * 256;
  const int tid = threadIdx.x;
  const int n   = n0 + tid;
  const float scale = 0.08838834764831845f;  // 128^-0.5

  __shared__ float sk[128 * 80];

  const float* kvb = kv + ((size_t)b * 2048 + h * 256) * 77;

  // zero pad columns once (phase 2 reuses; pad multiplied by p[77..79]=0 anyway,
  // but keep it clean so no NaN can form)
  for (int idx = tid; idx < 128 * 3; idx += 256) {
    int d = idx / 3, t = 77 + (idx - d * 3);
    sk[d * 80 + t] = 0.f;
  }
  // phase 1: K into LDS (source rows contiguous: 128*77 floats)
  for (int idx = tid; idx < 128 * 77; idx += 256) {
    int d = idx / 77, t = idx - d * 77;
    sk[d * 80 + t] = kvb[idx];
  }
  __syncthreads();

  float s[80];
#pragma unroll
  for (int t = 0; t < 80; ++t) s[t] = 0.f;

  const float* qp = q + ((size_t)b * 1024 + h * 128) * 1024 + n;
#pragma unroll 4
  for (int d = 0; d < 128; ++d) {
    float qd = qp[(size_t)d * 1024];
#pragma unroll
    for (int tc = 0; tc < 20; ++tc) {
      float4 k4 = *(const float4*)&sk[d * 80 + tc * 4];
      s[tc * 4 + 0] += qd * k4.x;
      s[tc * 4 + 1] += qd * k4.y;
      s[tc * 4 + 2] += qd * k4.z;
      s[tc * 4 + 3] += qd * k4.w;
    }
  }

  // softmax over t < 77 (scores scaled by `scale`)
  float m = -3.0e38f;
#pragma unroll
  for (int t = 0; t < 77; ++t) m = fmaxf(m, s[t]);
  float sum = 0.f;
#pragma unroll
  for (int t = 0; t < 77; ++t) {
    s[t] = __expf((s[t] - m) * scale);
    sum += s[t];
  }
  const float inv = 1.f / sum;
#pragma unroll
  for (int t = 0; t < 77; ++t) s[t] *= inv;
  s[77] = 0.f; s[78] = 0.f; s[79] = 0.f;

  __syncthreads();
  // phase 2: V into LDS (pad cols still zero)
  const float* vvb = kvb + 128 * 77;
  for (int idx = tid; idx < 128 * 77; idx += 256) {
    int d = idx / 77, t = idx - d * 77;
    sk[d * 80 + t] = vvb[idx];
  }
  __syncthreads();

  float* op = o + ((size_t)b * 1024 + h * 128) * 1024 + n;
#pragma unroll
  for (int dblk = 0; dblk < 8; ++dblk) {
    float acc[16];
#pragma unroll
    for (int dd = 0; dd < 16; ++dd) acc[dd] = 0.f;
#pragma unroll
    for (int dd = 0; dd < 16; ++dd) {
      const int d = dblk * 16 + dd;
#pragma unroll
      for (int tc = 0; tc < 20; ++tc) {
        float4 v4 = *(const float4*)&sk[d * 80 + tc * 4];
        acc[dd] += v4.x * s[tc * 4 + 0] + v4.y * s[tc * 4 + 1] +
                   v4.z * s[tc * 4 + 2] + v4.w * s[tc * 4 + 3];
      }
    }
#pragma unroll
    for (int dd = 0; dd < 16; ++dd)
      op[(size_t)(dblk * 16 + dd) * 1024] = acc[dd];
  }
}

// ---------------------------------------------------------------------------
extern "C" void kernel_launch(void* const* d_in, const int* in_sizes, int n_in,
                              void* d_out, int out_size, void* d_ws, size_t ws_size,
                              hipStream_t stream) {
  const float* Vx  = (const float*)d_in[0];
  const float* Tx  = (const float*)d_in[1];
  const float* Wq  = (const float*)d_in[2];
  const float* bq  = (const float*)d_in[3];
  const float* Wkv = (const float*)d_in[4];
  const float* bkv = (const float*)d_in[5];
  const float* Wp  = (const float*)d_in[6];
  const float* bp  = (const float*)d_in[7];
  float* out = (float*)d_out;

  char* ws = (char*)d_ws;
  float* q        = (float*)(ws);                      // 16*1024*1024*4 = 64 MiB
  float* attn_out = (float*)(ws + 67108864);           // 64 MiB
  float* kvbuf    = (float*)(ws + 2 * 67108864);       // 16*2048*77*4 ≈ 9.6 MiB

  dim3 gridP(16, 16, 16);  // (n-tiles, d-tiles, b)
  gemm_proj<<<gridP, 256, 0, stream>>>(Wq, Vx, bq, q);
  gemm_kv<<<dim3(16, 16), 256, 0, stream>>>(Wkv, Tx, bkv, kvbuf);
  attn_kernel<<<dim3(4, 8, 16), 256, 0, stream>>>(q, kvbuf, attn_out);
  gemm_proj<<<gridP, 256, 0, stream>>>(Wp, attn_out, bp, out);
}

// Round 2
// 1039.857 us; speedup vs baseline: 1.4317x; 1.4317x over previous
//
#include <hip/hip_runtime.h>
#include <cstdint>
#include <cstddef>

typedef unsigned short u16;
typedef __bf16 bf16x8 __attribute__((ext_vector_type(8)));
typedef float f32x4 __attribute__((ext_vector_type(4)));

typedef __attribute__((address_space(1))) const void global_cvoid;
typedef __attribute__((address_space(3))) void lds_void;

__device__ __forceinline__ void async16(void* lds, const void* g) {
  // 64 lanes x 16B: LDS dest = (uniform) lds + lane*16; global src per-lane.
  __builtin_amdgcn_global_load_lds((global_cvoid*)g, (lds_void*)lds, 16, 0, 0);
}

__device__ __forceinline__ u16 f2bf(float f) {  // RNE fp32 -> bf16 bits
  uint32_t u = __float_as_uint(f);
  return (u16)((u + 0x7fffu + ((u >> 16) & 1u)) >> 16);
}

// ---------------------------------------------------------------------------
// Pack W (A operand): out[d][3c+{0,1,2}] = {hi, hi, lo} of W[d][c].
// ---------------------------------------------------------------------------
__global__ __launch_bounds__(256) void pack_w(const float* __restrict__ W,
                                              u16* __restrict__ out) {
  int idx = blockIdx.x * 256 + threadIdx.x;  // 1024*1024 elements
  int d = idx >> 10, c = idx & 1023;
  float f = W[idx];
  u16 h = f2bf(f);
  float hf = __uint_as_float((uint32_t)h << 16);
  u16 l = f2bf(f - hf);
  u16* dst = out + (size_t)d * 3072 + 3 * c;
  dst[0] = h; dst[1] = h; dst[2] = l;
}

// ---------------------------------------------------------------------------
// Pack+transpose X (B operand): out[b][n][3c+{0,1,2}] = {hi, lo, hi} of X[b][c][n].
// 32x32 tiles via LDS. grid (n/32, c/32, B), 256 threads.
// ---------------------------------------------------------------------------
__global__ __launch_bounds__(256) void pack_x(const float* __restrict__ X,
                                              u16* __restrict__ out) {
  const int b = blockIdx.z, c0 = blockIdx.y * 32, n0 = blockIdx.x * 32;
  __shared__ float tile[32][33];
  const float* src = X + ((size_t)b * 1024 + c0) * 1024 + n0;
  const int tc = threadIdx.x >> 5, tn = threadIdx.x & 31;
#pragma unroll
  for (int i = 0; i < 4; ++i)
    tile[tc + i * 8][tn] = src[(size_t)(tc + i * 8) * 1024 + tn];
  __syncthreads();
  const int nl = threadIdx.x >> 3, cg = (threadIdx.x & 7) * 4;
  u16 h[4], l[4];
#pragma unroll
  for (int u = 0; u < 4; ++u) {
    float f = tile[cg + u][nl];
    h[u] = f2bf(f);
    float hf = __uint_as_float((uint32_t)h[u] << 16);
    l[u] = f2bf(f - hf);
  }
  // stream: h0 l0 h0 | h1 l1 h1 | h2 l2 h2 | h3 l3 h3  (12 u16 = 24B, 8B-aligned)
  uint32_t* dst = (uint32_t*)(out + ((size_t)b * 1024 + n0 + nl) * 3072 +
                              (size_t)(c0 + cg) * 3);
  dst[0] = (uint32_t)h[0] | ((uint32_t)l[0] << 16);
  dst[1] = (uint32_t)h[0] | ((uint32_t)h[1] << 16);
  dst[2] = (uint32_t)l[1] | ((uint32_t)h[1] << 16);
  dst[3] = (uint32_t)h[2] | ((uint32_t)l[2] << 16);
  dst[4] = (uint32_t)h[2] | ((uint32_t)h[3] << 16);
  dst[5] = (uint32_t)l[3] | ((uint32_t)h[3] << 16);
}

// ---------------------------------------------------------------------------
// MFMA GEMM: Y[b][d][n] = sum_{k'} Apk[d][k'] * Bpk[b][n][k'] + bias[d]
// K' = 3072 (bf16x3-packed). 128x128 tile, 4 waves 2x2, 16x16x32 bf16 MFMA,
// global_load_lds(16B) staging; LDS layout == fragment layout (linear b128).
// ---------------------------------------------------------------------------
__global__ __launch_bounds__(256) void gemm_mfma(
    const u16* __restrict__ Apk,   // [1024][3072] {h,h,l}
    const u16* __restrict__ Bpk,   // [16][1024][3072] {h,l,h}
    const float* __restrict__ bias,
    float* __restrict__ Y)         // [16][1024][1024]
{
  const int b  = blockIdx.z;
  const int d0 = blockIdx.y * 128;
  const int n0 = blockIdx.x * 128;
  const int tid  = threadIdx.x;
  const int lane = tid & 63;
  const int w    = tid >> 6;
  const int wm   = w >> 1, wn = w & 1;

  __shared__ __align__(16) char smem[16384];
  char* smA = smem;          // 8 KB: [mt 0..7][lane][16B]
  char* smB = smem + 8192;   // 8 KB: [nt 0..7][lane][16B]

  const int lr = lane & 15;        // row within 16 (m or n)
  const int lk = (lane >> 4) * 8;  // k offset (elements)

  const u16* Bb = Bpk + (size_t)b * 1024 * 3072;
  const char* gA0 = (const char*)(Apk + ((size_t)(d0 + (w * 2 + 0) * 16 + lr) * 3072 + lk));
  const char* gA1 = (const char*)(Apk + ((size_t)(d0 + (w * 2 + 1) * 16 + lr) * 3072 + lk));
  const char* gB0 = (const char*)(Bb  + ((size_t)(n0 + (w * 2 + 0) * 16 + lr) * 3072 + lk));
  const char* gB1 = (const char*)(Bb  + ((size_t)(n0 + (w * 2 + 1) * 16 + lr) * 3072 + lk));

  f32x4 acc[4][4];
#pragma unroll
  for (int i = 0; i < 4; ++i)
#pragma unroll
    for (int j = 0; j < 4; ++j) acc[i][j] = (f32x4){0.f, 0.f, 0.f, 0.f};

  for (int ks = 0; ks < 96; ++ks) {
    __syncthreads();  // all waves done reading previous tiles
    async16(smA + (w * 2 + 0) * 1024, gA0);
    async16(smA + (w * 2 + 1) * 1024, gA1);
    async16(smB + (w * 2 + 0) * 1024, gB0);
    async16(smB + (w * 2 + 1) * 1024, gB1);
    gA0 += 64; gA1 += 64; gB0 += 64; gB1 += 64;  // advance 32 k-elems
    __syncthreads();  // implies vmcnt drain of the async loads

    bf16x8 af[4], bf[4];
#pragma unroll
    for (int i = 0; i < 4; ++i)
      af[i] = *(const bf16x8*)(smA + (wm * 4 + i) * 1024 + lane * 16);
#pragma unroll
    for (int j = 0; j < 4; ++j)
      bf[j] = *(const bf16x8*)(smB + (wn * 4 + j) * 1024 + lane * 16);
#pragma unroll
    for (int i = 0; i < 4; ++i)
#pragma unroll
      for (int j = 0; j < 4; ++j)
        acc[i][j] = __builtin_amdgcn_mfma_f32_16x16x32_bf16(af[i], bf[j], acc[i][j], 0, 0, 0);
  }

  // Epilogue: D row = (lane>>4)*4 + reg, col = lane&15 (m89-verified layout)
#pragma unroll
  for (int i = 0; i < 4; ++i) {
    const int dbase = d0 + wm * 64 + i * 16 + (lane >> 4) * 4;
    const float4 bv = *(const float4*)(bias + dbase);
#pragma unroll
    for (int j = 0; j < 4; ++j) {
      const int n = n0 + wn * 64 + j * 16 + lr;
      float* yp = Y + ((size_t)b * 1024 + dbase) * 1024 + n;
      yp[0]        = acc[i][j].x + bv.x;
      yp[1024]     = acc[i][j].y + bv.y;
      yp[2 * 1024] = acc[i][j].z + bv.z;
      yp[3 * 1024] = acc[i][j].w + bv.w;
    }
  }
}

// ---------------------------------------------------------------------------
// KV projection (fp32 VALU, unchanged from round 1).
// ---------------------------------------------------------------------------
__global__ __launch_bounds__(256) void gemm_kv(
    const float* __restrict__ Wkv, const float* __restrict__ Tx,
    const float* __restrict__ bkv, float* __restrict__ kvout)
{
  const int b   = blockIdx.y;
  const int e0  = blockIdx.x * 128;
  const int tid = threadIdx.x;

  __shared__ float Wts[32][132];
  __shared__ float Txs[32][80];

  const int row0 = (tid >> 2) * 2;
  const int tb   = (tid & 3) * 20;

  float acc[2][20];
#pragma unroll
  for (int r = 0; r < 2; ++r)
#pragma unroll
    for (int j = 0; j < 20; ++j) acc[r][j] = 0.f;

  for (int idx = tid; idx < 32 * 3; idx += 256) {
    int r = idx / 3, c = 77 + (idx - r * 3);
    Txs[r][c] = 0.f;
  }

  const int wrow = tid >> 1;
  const int wkg  = (tid & 1) * 16;

  for (int k0 = 0; k0 < 1024; k0 += 32) {
    __syncthreads();
#pragma unroll
    for (int i = 0; i < 4; ++i) {
      float4 w = *(const float4*)(Wkv + (size_t)(e0 + wrow) * 1024 + k0 + wkg + i * 4);
      Wts[wkg + i * 4 + 0][wrow] = w.x;
      Wts[wkg + i * 4 + 1][wrow] = w.y;
      Wts[wkg + i * 4 + 2][wrow] = w.z;
      Wts[wkg + i * 4 + 3][wrow] = w.w;
    }
    const float* src = Tx + ((size_t)b * 1024 + k0) * 77;
    for (int idx = tid; idx < 32 * 77; idx += 256) {
      int r = idx / 77, c = idx - r * 77;
      Txs[r][c] = src[idx];
    }
    __syncthreads();
#pragma unroll
    for (int kk = 0; kk < 32; ++kk) {
      float2 w = *(const float2*)&Wts[kk][row0];
#pragma unroll
      for (int tc = 0; tc < 5; ++tc) {
        float4 x4 = *(const float4*)&Txs[kk][tb + tc * 4];
        const float* xf = (const float*)&x4;
#pragma unroll
        for (int j = 0; j < 4; ++j) {
          acc[0][tc * 4 + j] += w.x * xf[j];
          acc[1][tc * 4 + j] += w.y * xf[j];
        }
      }
    }
  }

#pragma unroll
  for (int r = 0; r < 2; ++r) {
    const int e = e0 + row0 + r;
    const float bv = bkv[e];
    float* dst = kvout + ((size_t)b * 2048 + e) * 77;
#pragma unroll
    for (int j = 0; j < 20; ++j) {
      int t = tb + j;
      if (t < 77) dst[t] = acc[r][j] + bv;
    }
  }
}

// ---------------------------------------------------------------------------
// Fused attention, 2 n-values per thread (halves LDS read traffic).
// Block: 256 threads over 512 n; grid (2, NH=8, B=16).
// ---------------------------------------------------------------------------
__global__ __launch_bounds__(256, 1) void attn_kernel2(
    const float* __restrict__ q,   // [B][1024][1024]
    const float* __restrict__ kv,  // [B][2048][77]
    float* __restrict__ o)         // [B][1024][1024]
{
  const int b   = blockIdx.z;
  const int h   = blockIdx.y;
  const int n0  = blockIdx.x * 512;
  const int tid = threadIdx.x;
  const float scale = 0.08838834764831845f;  // 128^-0.5

  __shared__ float sk[128 * 80];

  const float* kvb = kv + ((size_t)b * 2048 + h * 256) * 77;

  for (int idx = tid; idx < 128 * 3; idx += 256) {
    int d = idx / 3, t = 77 + (idx - d * 3);
    sk[d * 80 + t] = 0.f;
  }
  for (int idx = tid; idx < 128 * 77; idx += 256) {
    int d = idx / 77, t = idx - d * 77;
    sk[d * 80 + t] = kvb[idx];
  }
  __syncthreads();

  float s0[80], s1[80];
#pragma unroll
  for (int t = 0; t < 80; ++t) { s0[t] = 0.f; s1[t] = 0.f; }

  const float* qp = q + ((size_t)b * 1024 + h * 128) * 1024 + n0 + tid;
#pragma unroll 4
  for (int d = 0; d < 128; ++d) {
    float qa = qp[(size_t)d * 1024];
    float qb = qp[(size_t)d * 1024 + 256];
#pragma unroll
    for (int tc = 0; tc < 20; ++tc) {
      float4 k4 = *(const float4*)&sk[d * 80 + tc * 4];
      s0[tc * 4 + 0] += qa * k4.x; s1[tc * 4 + 0] += qb * k4.x;
      s0[tc * 4 + 1] += qa * k4.y; s1[tc * 4 + 1] += qb * k4.y;
      s0[tc * 4 + 2] += qa * k4.z; s1[tc * 4 + 2] += qb * k4.z;
      s0[tc * 4 + 3] += qa * k4.w; s1[tc * 4 + 3] += qb * k4.w;
    }
  }

  // softmax (independently for the two n values)
  float m0 = -3.0e38f, m1 = -3.0e38f;
#pragma unroll
  for (int t = 0; t < 77; ++t) { m0 = fmaxf(m0, s0[t]); m1 = fmaxf(m1, s1[t]); }
  float sum0 = 0.f, sum1 = 0.f;
#pragma unroll
  for (int t = 0; t < 77; ++t) {
    s0[t] = __expf((s0[t] - m0) * scale); sum0 += s0[t];
    s1[t] = __expf((s1[t] - m1) * scale); sum1 += s1[t];
  }
  const float i0 = 1.f / sum0, i1 = 1.f / sum1;
#pragma unroll
  for (int t = 0; t < 77; ++t) { s0[t] *= i0; s1[t] *= i1; }
  s0[77] = s0[78] = s0[79] = 0.f;
  s1[77] = s1[78] = s1[79] = 0.f;

  __syncthreads();
  const float* vvb = kvb + 128 * 77;
  for (int idx = tid; idx < 128 * 77; idx += 256) {
    int d = idx / 77, t = idx - d * 77;
    sk[d * 80 + t] = vvb[idx];
  }
  __syncthreads();

  float* op = o + ((size_t)b * 1024 + h * 128) * 1024 + n0 + tid;
#pragma unroll
  for (int dblk = 0; dblk < 16; ++dblk) {
    float a0[8], a1[8];
#pragma unroll
    for (int dd = 0; dd < 8; ++dd) { a0[dd] = 0.f; a1[dd] = 0.f; }
#pragma unroll
    for (int dd = 0; dd < 8; ++dd) {
      const int d = dblk * 8 + dd;
#pragma unroll
      for (int tc = 0; tc < 20; ++tc) {
        float4 v4 = *(const float4*)&sk[d * 80 + tc * 4];
        a0[dd] += v4.x * s0[tc * 4 + 0] + v4.y * s0[tc * 4 + 1] +
                  v4.z * s0[tc * 4 + 2] + v4.w * s0[tc * 4 + 3];
        a1[dd] += v4.x * s1[tc * 4 + 0] + v4.y * s1[tc * 4 + 1] +
                  v4.z * s1[tc * 4 + 2] + v4.w * s1[tc * 4 + 3];
      }
    }
#pragma unroll
    for (int dd = 0; dd < 8; ++dd) {
      op[(size_t)(dblk * 8 + dd) * 1024]       = a0[dd];
      op[(size_t)(dblk * 8 + dd) * 1024 + 256] = a1[dd];
    }
  }
}

// ---------------------------------------------------------------------------
extern "C" void kernel_launch(void* const* d_in, const int* in_sizes, int n_in,
                              void* d_out, int out_size, void* d_ws, size_t ws_size,
                              hipStream_t stream) {
  const float* Vx  = (const float*)d_in[0];
  const float* Tx  = (const float*)d_in[1];
  const float* Wq  = (const float*)d_in[2];
  const float* bq  = (const float*)d_in[3];
  const float* Wkv = (const float*)d_in[4];
  const float* bkv = (const float*)d_in[5];
  const float* Wp  = (const float*)d_in[6];
  const float* bp  = (const float*)d_in[7];
  float* out = (float*)d_out;

  char* ws = (char*)d_ws;
  const size_t MiB = (size_t)1 << 20;
  float* q        = (float*)(ws + 0);          // 64 MiB
  float* attn_out = (float*)(ws + 64 * MiB);   // 64 MiB
  float* kvbuf    = (float*)(ws + 128 * MiB);  // 9.63 MiB
  u16*   WqPk     = (u16*)(ws + 138 * MiB);    // 6 MiB
  u16*   WpPk     = (u16*)(ws + 144 * MiB);    // 6 MiB
  u16*   Xpk      = (u16*)(ws + 150 * MiB);    // 96 MiB  (reused for attn_out pack)

  pack_w<<<4096, 256, 0, stream>>>(Wq, WqPk);
  pack_w<<<4096, 256, 0, stream>>>(Wp, WpPk);
  pack_x<<<dim3(32, 32, 16), 256, 0, stream>>>(Vx, Xpk);
  gemm_kv<<<dim3(16, 16), 256, 0, stream>>>(Wkv, Tx, bkv, kvbuf);
  gemm_mfma<<<dim3(8, 8, 16), 256, 0, stream>>>(WqPk, Xpk, bq, q);
  attn_kernel2<<<dim3(2, 8, 16), 256, 0, stream>>>(q, kvbuf, attn_out);
  pack_x<<<dim3(32, 32, 16), 256, 0, stream>>>(attn_out, Xpk);
  gemm_mfma<<<dim3(8, 8, 16), 256, 0, stream>>>(WpPk, Xpk, bp, out);
}